// Round 11
// baseline (267.271 us; speedup 1.0000x reference)
//
#include <hip/hip_runtime.h>

#define BB 8
#define CC 256
#define DD 128
#define NN 4096

#define LOG2E 1.44269504f
#define MSHIFT 32.0f  // fixed softmax shift (base-2 domain); |S*log2e| << 32 always

typedef __attribute__((ext_vector_type(8))) short short8;
typedef __attribute__((ext_vector_type(4))) short short4v;
typedef __attribute__((ext_vector_type(4))) float f32x4;
typedef __attribute__((ext_vector_type(16))) float f32x16;
typedef __attribute__((ext_vector_type(4))) unsigned int u32x4;

static __device__ __forceinline__ unsigned short f2bf(float f) {
    unsigned u = __builtin_bit_cast(unsigned, f);
    u += 0x7FFFu + ((u >> 16) & 1u);
    return (unsigned short)(u >> 16);
}
static __device__ __forceinline__ float bf2f(unsigned short h) {
    unsigned u = ((unsigned)h) << 16;
    return __builtin_bit_cast(float, u);
}
static __device__ __forceinline__ short8 pack8(float4 a, float4 b) {
    short8 r;
    r[0] = (short)f2bf(a.x); r[1] = (short)f2bf(a.y);
    r[2] = (short)f2bf(a.z); r[3] = (short)f2bf(a.w);
    r[4] = (short)f2bf(b.x); r[5] = (short)f2bf(b.y);
    r[6] = (short)f2bf(b.z); r[7] = (short)f2bf(b.w);
    return r;
}
// packed f32x2 -> bf16x2 (RNE); element 0 in low 16 bits
static __device__ __forceinline__ unsigned cvtpk_bf16(float lo, float hi) {
    unsigned r;
    asm("v_cvt_pk_bf16_f32 %0, %1, %2" : "=v"(r) : "v"(lo), "v"(hi));
    return r;
}
// swap upper 32 lanes of a with lower 32 lanes of b (T12 primitive)
static __device__ __forceinline__ void pl32swap(unsigned &a, unsigned &b) {
#if __has_builtin(__builtin_amdgcn_permlane32_swap)
    auto r = __builtin_amdgcn_permlane32_swap((int)a, (int)b, false, false);
    a = (unsigned)r[0]; b = (unsigned)r[1];
#else
    asm("v_permlane32_swap_b32 %0, %1" : "+v"(a), "+v"(b));
#endif
}
// async global->LDS DMA, 16 B/lane: LDS dest = wave-uniform base + lane*16 (m97/m104)
static __device__ __forceinline__ void gll16(const void* g, void* l) {
    __builtin_amdgcn_global_load_lds(
        (const __attribute__((address_space(1))) unsigned int*)g,
        (__attribute__((address_space(3))) unsigned int*)l, 16, 0, 0);
}
// counted VMEM wait (T4): literal-immediate variants; memory clobber pins mem ops
#define VMWAIT(N) asm volatile("s_waitcnt vmcnt(" #N ")" ::: "memory")

// ---------------- kernel 2: FUSED projections v3 — high-TLP small blocks ----------------
// grid (NN/32, BB) = 1024 blocks, block 256 = 4 waves (wave owns d-slice wave*32); nb=32.
// 4 blocks/CU (launch_bounds(256,4); acc = 48 VGPR via shared B-frags + transient W-frags)
// -> 16 waves/CU and 4 independent barrier domains vs the old 1x512-thread block (r1->r2
// flash lesson applied to proj). Per kc chunk: stage x^T [32n][64c] bf16 (col swizzle
// (c + 8*(n>>4)) & 63), prefetch next chunk's x into regs during MFMA. 3 projections
// share the B-fragments: 24 MFMA + 12 pack8 per chunk per wave.
// Outputs: Q=theta*log2e [n][d], K=phi [n][d], Vt=g [d][n]. x read once.
__global__ __launch_bounds__(256, 4) void k_proj(
        const float* __restrict__ x,
        const float* __restrict__ w_phi, const float* __restrict__ b_phi,
        const float* __restrict__ w_theta, const float* __restrict__ b_theta,
        const float* __restrict__ w_g, const float* __restrict__ b_g,
        unsigned short* __restrict__ qws, unsigned short* __restrict__ kws,
        unsigned short* __restrict__ vtws) {
    __shared__ __align__(16) unsigned short xs[32][72];      // staged x^T chunk (4608 B)
    __shared__ __align__(16) unsigned short rp[128][40];     // Vt repack (10240 B); Q/K view [32][136] (8704 B)
    int nb = blockIdx.x * 32, b = blockIdx.y;
    int t = threadIdx.x, lane = t & 63, wave = t >> 6;       // wave 0..3 = d-slice
    int l16 = lane & 15, l4 = lane >> 4;

    f32x4 acc[3][2][2];  // [proj][mf][nf]
#pragma unroll
    for (int p = 0; p < 3; p++)
#pragma unroll
        for (int mf = 0; mf < 2; mf++)
#pragma unroll
            for (int nf = 0; nf < 2; nf++)
#pragma unroll
                for (int e = 0; e < 4; e++) acc[p][mf][nf][e] = 0.f;

    const float* xpb = x + (size_t)b * CC * NN;  // [c][n]
    int cr = t >> 2;                // 0..63: c within 64-chunk
    int ng = t & 3;                 // n-group (8 n each)
    int wcol = (cr + 8 * (ng >> 1)) & 63;  // swizzled col: (c + 8*(n>>4)) & 63, n=ng*8+j

    float4 xv0, xv1;
    {   // preload chunk 0 (2 float4/thread: row cr, n = nb+ng*8..+8)
        const float* src = xpb + (size_t)cr * NN + nb + ng * 8;
        xv0 = *(const float4*)src; xv1 = *(const float4*)(src + 4);
    }

    for (int kc = 0; kc < 4; kc++) {
        __syncthreads();  // prev chunk's xs readers done
        {   // write staged regs -> xs (col constant per thread: n stays in one 16-block)
            int n0 = ng * 8;
            xs[n0 + 0][wcol] = f2bf(xv0.x);
            xs[n0 + 1][wcol] = f2bf(xv0.y);
            xs[n0 + 2][wcol] = f2bf(xv0.z);
            xs[n0 + 3][wcol] = f2bf(xv0.w);
            xs[n0 + 4][wcol] = f2bf(xv1.x);
            xs[n0 + 5][wcol] = f2bf(xv1.y);
            xs[n0 + 6][wcol] = f2bf(xv1.z);
            xs[n0 + 7][wcol] = f2bf(xv1.w);
        }
        __syncthreads();
        if (kc < 3) {  // T14: prefetch next chunk's x; latency hides under MFMA below
            const float* src = xpb + (size_t)((kc + 1) * 64 + cr) * NN + nb + ng * 8;
            xv0 = *(const float4*)src; xv1 = *(const float4*)(src + 4);
        }
        // shared B-fragments (x^T): n-row = nf*16+l16, cols (ic*32 + l4*8 + 8*nf) & 63
        short8 bfr[2][2];  // [nf][ic]
#pragma unroll
        for (int nf = 0; nf < 2; nf++)
#pragma unroll
            for (int ic = 0; ic < 2; ic++)
                bfr[nf][ic] = *(const short8*)&xs[nf * 16 + l16][(ic * 32 + l4 * 8 + 8 * nf) & 63];

        int c0k = kc * 64;
#pragma unroll
        for (int p = 0; p < 3; p++) {
            const float* W = (p == 0) ? w_theta : (p == 1) ? w_phi : w_g;
            short8 af[2][2];  // [mf][ic] — transient, reused across p
#pragma unroll
            for (int mf = 0; mf < 2; mf++)
#pragma unroll
                for (int ic = 0; ic < 2; ic++) {
                    int d = wave * 32 + mf * 16 + l16;
                    const float* wp = W + d * CC + c0k + ic * 32 + l4 * 8;
                    af[mf][ic] = pack8(*(const float4*)wp, *(const float4*)(wp + 4));
                }
#pragma unroll
            for (int nf = 0; nf < 2; nf++)
#pragma unroll
                for (int ic = 0; ic < 2; ic++)
#pragma unroll
                    for (int mf = 0; mf < 2; mf++)
                        acc[p][mf][nf] = __builtin_amdgcn_mfma_f32_16x16x32_bf16(
                            af[mf][ic], bfr[nf][ic], acc[p][mf][nf], 0, 0, 0);
        }
    }
    // acc C-layout: col(l16) = n-within-frag, row(l4*4+r) = d-within-frag

    // ---- Q (theta*log2e) then K (phi), [n][d] via rp view [32][136] ----
    unsigned short (*rq)[136] = (unsigned short (*)[136])rp;
#pragma unroll
    for (int pr = 0; pr < 2; pr++) {
        float scl = (pr == 0) ? LOG2E : 1.0f;
        const float* bias = (pr == 0) ? b_theta : b_phi;
#pragma unroll
        for (int mf = 0; mf < 2; mf++) {
            int d0 = wave * 32 + mf * 16 + l4 * 4;
            float bb[4];
#pragma unroll
            for (int r = 0; r < 4; r++) bb[r] = bias[d0 + r];
#pragma unroll
            for (int nf = 0; nf < 2; nf++) {
                short4v pk;
#pragma unroll
                for (int r = 0; r < 4; r++) pk[r] = (short)f2bf((acc[pr][mf][nf][r] + bb[r]) * scl);
                *(short4v*)&rq[nf * 16 + l16][d0] = pk;
            }
        }
        __syncthreads();
        {
            unsigned short* outp = (pr == 0 ? qws : kws) + (size_t)b * NN * DD;
#pragma unroll
            for (int i = 0; i < 2; i++) {
                int idx = t + 256 * i;  // 0..511
                int n = idx >> 4, dd = (idx & 15) * 8;
                *(short8*)(outp + (size_t)(nb + n) * DD + dd) = *(const short8*)&rq[n][dd];
            }
        }
        __syncthreads();
    }

    // ---- Vt = g, [d][n] via rp [128][40] ----
#pragma unroll
    for (int mf = 0; mf < 2; mf++) {
        int drow = wave * 32 + mf * 16 + l4 * 4;
        float bb[4];
#pragma unroll
        for (int r = 0; r < 4; r++) bb[r] = b_g[drow + r];
#pragma unroll
        for (int nf = 0; nf < 2; nf++)
#pragma unroll
            for (int r = 0; r < 4; r++)
                rp[drow + r][nf * 16 + l16] = f2bf(acc[2][mf][nf][r] + bb[r]);
    }
    __syncthreads();
    {
        unsigned short* outp = vtws + (size_t)b * DD * NN;
#pragma unroll
        for (int i = 0; i < 2; i++) {
            int idx = t + 256 * i;  // 0..511
            int d = idx >> 2, n0s = (idx & 3) * 8;
            *(short8*)(outp + (size_t)d * NN + nb + n0s) = *(const short8*)&rp[d][n0s];
        }
    }
}

// ---------------- kernel 3: flash attention — ring-4 + T15 pipeline (QK(t+1) ∥ SM/PV(t)) --
// r8-verified ring-4/counted-vmcnt skeleton. T15: iteration t interleaves softmax(t)+PV(t)
// (VALU + 8 MFMA) with QK^T(t+1) (8 MFMA, independent) — exp2/cvt ops sit between the
// dependent QK MFMAs so the chain latency is hidden (r9 lesson: bare dist-1 chain stalls).
// vmcnt(4) before the barrier drains tile t+1 (FIFO: outstanding t+1(4)+t+2(4)=8 -> 4);
// wait-BEFORE-barrier publishes all waves' segments. Ring-4 slot distances: write t+2,
// read K t+1, read V t, laggard reads t-1 -> pairwise distinct mod 4. All pipeline state
// in statically-named registers (macro, no lambda - r3 lesson). Final iter's QK reads a
// stale slot into a dead register (branch-free). grid 512 = 2 blocks/CU, 8 waves/CU.
// FROZEN THIS ROUND (control): 92.9-93.2 us verified r8/r10.
#define QKSTEP(SN, KBN, KC) \
    SN = __builtin_amdgcn_mfma_f32_32x32x16_bf16( \
        *(const short8*)((KBN) + kvo[KC]), qreg[KC], SN, 0, 0, 0);

#define PABUILD(PA, Pa, Pb, Pc, Pd, Pe, Pf_, Pg, Ph) {                                \
    unsigned x0 = cvtpk_bf16(Pa, Pb);                                                 \
    unsigned x1 = cvtpk_bf16(Pc, Pd);                                                 \
    unsigned y0 = cvtpk_bf16(Pe, Pf_);                                                \
    unsigned y1 = cvtpk_bf16(Pg, Ph);                                                 \
    pl32swap(x0, y0); pl32swap(x1, y1);                                               \
    PA[0] = x0; PA[1] = x1; PA[2] = y0; PA[3] = y1; }

#define FBODY(IT, SC, SN) {                                                           \
    if ((IT) + 2 < NIT) {                                                             \
        int mb2 = kbase + ((IT) + 2) * 32;                                            \
        char* W = (char*)smem + (((IT) + 2) & 3) * 16384;                             \
        gll16(kp + (size_t)mb2 * DD + koff[0], W + (wave * 2 + 0) * 1024);            \
        gll16(kp + (size_t)mb2 * DD + koff[1], W + (wave * 2 + 1) * 1024);            \
        gll16(vp + mb2 + voff[0], W + 8192 + (wave * 2 + 0) * 1024);                  \
        gll16(vp + mb2 + voff[1], W + 8192 + (wave * 2 + 1) * 1024);                  \
        VMWAIT(4);                                                                    \
    } else {                                                                          \
        VMWAIT(0);                                                                    \
    }                                                                                 \
    __builtin_amdgcn_s_barrier();                                                     \
    asm volatile("" ::: "memory");                                                    \
    char* KbN = (char*)smem + (((IT) + 1) & 3) * 16384;                               \
    char* Vb  = (char*)smem + ((IT) & 3) * 16384 + 8192;                              \
    _Pragma("unroll") for (int e = 0; e < 16; e++) SN[e] = -MSHIFT;                   \
    float p0, p1, p2, p3, p4, p5, p6, p7, p8, p9, p10, p11, p12, p13, p14, p15;       \
    __builtin_amdgcn_s_setprio(1);                                                    \
    p0 = __builtin_exp2f(SC[0]);  lsum0 += p0;                                        \
    p1 = __builtin_exp2f(SC[1]);  lsum1 += p1;                                        \
    p2 = __builtin_exp2f(SC[2]);  lsum0 += p2;                                        \
    p3 = __builtin_exp2f(SC[3]);  lsum1 += p3;                                        \
    QKSTEP(SN, KbN, 0) QKSTEP(SN, KbN, 1)                                             \
    p4 = __builtin_exp2f(SC[4]);  lsum0 += p4;                                        \
    p5 = __builtin_exp2f(SC[5]);  lsum1 += p5;                                        \
    p6 = __builtin_exp2f(SC[6]);  lsum0 += p6;                                        \
    p7 = __builtin_exp2f(SC[7]);  lsum1 += p7;                                        \
    QKSTEP(SN, KbN, 2) QKSTEP(SN, KbN, 3)                                             \
    u32x4 paA; PABUILD(paA, p0, p1, p2, p3, p4, p5, p6, p7)                           \
    p8  = __builtin_exp2f(SC[8]);  lsum0 += p8;                                       \
    p9  = __builtin_exp2f(SC[9]);  lsum1 += p9;                                       \
    p10 = __builtin_exp2f(SC[10]); lsum0 += p10;                                      \
    p11 = __builtin_exp2f(SC[11]); lsum1 += p11;                                      \
    QKSTEP(SN, KbN, 4) QKSTEP(SN, KbN, 5)                                             \
    p12 = __builtin_exp2f(SC[12]); lsum0 += p12;                                      \
    p13 = __builtin_exp2f(SC[13]); lsum1 += p13;                                      \
    p14 = __builtin_exp2f(SC[14]); lsum0 += p14;                                      \
    p15 = __builtin_exp2f(SC[15]); lsum1 += p15;                                      \
    QKSTEP(SN, KbN, 6) QKSTEP(SN, KbN, 7)                                             \
    u32x4 paB; PABUILD(paB, p8, p9, p10, p11, p12, p13, p14, p15)                     \
    o[0] = __builtin_amdgcn_mfma_f32_32x32x16_bf16(                                   \
        __builtin_bit_cast(short8, paA), *(const short8*)(Vb + 0 * 2048 + vvo[0]), o[0], 0, 0, 0); \
    o[1] = __builtin_amdgcn_mfma_f32_32x32x16_bf16(                                   \
        __builtin_bit_cast(short8, paA), *(const short8*)(Vb + 1 * 2048 + vvo[0]), o[1], 0, 0, 0); \
    o[2] = __builtin_amdgcn_mfma_f32_32x32x16_bf16(                                   \
        __builtin_bit_cast(short8, paA), *(const short8*)(Vb + 2 * 2048 + vvo[0]), o[2], 0, 0, 0); \
    o[3] = __builtin_amdgcn_mfma_f32_32x32x16_bf16(                                   \
        __builtin_bit_cast(short8, paA), *(const short8*)(Vb + 3 * 2048 + vvo[0]), o[3], 0, 0, 0); \
    o[0] = __builtin_amdgcn_mfma_f32_32x32x16_bf16(                                   \
        __builtin_bit_cast(short8, paB), *(const short8*)(Vb + 0 * 2048 + vvo[1]), o[0], 0, 0, 0); \
    o[1] = __builtin_amdgcn_mfma_f32_32x32x16_bf16(                                   \
        __builtin_bit_cast(short8, paB), *(const short8*)(Vb + 1 * 2048 + vvo[1]), o[1], 0, 0, 0); \
    o[2] = __builtin_amdgcn_mfma_f32_32x32x16_bf16(                                   \
        __builtin_bit_cast(short8, paB), *(const short8*)(Vb + 2 * 2048 + vvo[1]), o[2], 0, 0, 0); \
    o[3] = __builtin_amdgcn_mfma_f32_32x32x16_bf16(                                   \
        __builtin_bit_cast(short8, paB), *(const short8*)(Vb + 3 * 2048 + vvo[1]), o[3], 0, 0, 0); \
    __builtin_amdgcn_s_setprio(0);                                                    \
}

__global__ __launch_bounds__(256, 2) void k_flash(
        const unsigned short* __restrict__ q, const unsigned short* __restrict__ kk,
        const unsigned short* __restrict__ vt, unsigned short* __restrict__ opart,
        float* __restrict__ lsums) {
    __shared__ __align__(16) unsigned char smem[65536];
    // buf i at smem + i*16384: K (32 rows x 256 B) at +0, V (128 rows x 64 B) at +8192

    int bid = blockIdx.x;
    int b   = bid & 7;           // batch -> XCD (round-robin dispatch): K/V L2-resident
    int rem = bid >> 3;          // 0..63
    int ks  = rem >> 5;          // 0..1
    int qt  = rem & 31;          // 0..31
    int qb  = qt * 128;

    int t = threadIdx.x, lane = t & 63, wave = t >> 6;  // wave 0..3
    int l31 = lane & 31, hi = lane >> 5;

    const unsigned short* qp = q  + (size_t)b * NN * DD;
    const unsigned short* kp = kk + (size_t)b * NN * DD;
    const unsigned short* vp = vt + (size_t)b * DD * NN;

    // Q fragments (B-operand of swapped QK^T): lane holds Q[qb+w*32+l31][kc*16+hi*8+e]
    short8 qreg[8];
    {
        int qrow = qb + wave * 32 + l31;
#pragma unroll
        for (int kc = 0; kc < 8; kc++)
            qreg[kc] = *(const short8*)(qp + (size_t)qrow * DD + kc * 16 + hi * 8);
    }

    // per-lane DMA source offsets (elements): wave stages 2 K-segs + 2 V-segs (1024 B each).
    // K seg s covers rows 4s..4s+3; src chunk = c' ^ (row&7) -> LDS[row][c'] = swizzled.
    // V seg s covers d-rows 16s..16s+15; src chunk = c' ^ ((row^(row>>2))&3).
    int koff[2], voff[2];
#pragma unroll
    for (int j = 0; j < 2; j++) {
        int seg = wave * 2 + j;
        int krow = seg * 4 + (lane >> 4);
        koff[j] = krow * DD + (((lane & 15) ^ (krow & 7)) << 3);
        int vrow = seg * 16 + (lane >> 2);
        voff[j] = vrow * NN + (((lane & 3) ^ ((vrow ^ (vrow >> 2)) & 3)) << 3);
    }

    // loop-invariant LDS READ byte-offsets (within a ring slot):
    // K: kvo[kc] = l31*256 + (((kc<<1|hi) ^ (l31&7)) << 4)
    // V: vvo[c]  = l31*64  + (((c<<1|hi) ^ ((l31^(l31>>2))&3)) << 4); read at +df*2048
    int kvo[8], vvo[2];
    {
        int e = l31 & 7;
#pragma unroll
        for (int kc = 0; kc < 8; kc++)
            kvo[kc] = l31 * 256 + ((((kc << 1) | hi) ^ e) << 4);
        int sw = (l31 ^ (l31 >> 2)) & 3;
#pragma unroll
        for (int c = 0; c < 2; c++)
            vvo[c] = l31 * 64 + ((((c << 1) | hi) ^ sw) << 4);
    }

    f32x16 o[4];
#pragma unroll
    for (int df = 0; df < 4; df++)
#pragma unroll
        for (int e = 0; e < 16; e++) o[df][e] = 0.f;
    float lsum0 = 0.f, lsum1 = 0.f;

    int kbase = ks * (NN / 2);
    const int NIT = (NN / 2) / 32;  // 64

    // prologue: issue DMA for tiles 0 and 1; drain tile 0; QK(0) -> s0
#pragma unroll
    for (int pt = 0; pt < 2; pt++) {
        int mb = kbase + pt * 32;
        char* Kb = (char*)smem + pt * 16384;
#pragma unroll
        for (int j = 0; j < 2; j++) {
            int seg = wave * 2 + j;
            gll16(kp + (size_t)mb * DD + koff[j], Kb + seg * 1024);
            gll16(vp + mb + voff[j], Kb + 8192 + seg * 1024);
        }
    }
    VMWAIT(4);
    __builtin_amdgcn_s_barrier();
    asm volatile("" ::: "memory");

    f32x16 s0, s1;
#pragma unroll
    for (int e = 0; e < 16; e++) s0[e] = -MSHIFT;
    {
        char* Kb0 = (char*)smem;
        __builtin_amdgcn_s_setprio(1);
        QKSTEP(s0, Kb0, 0) QKSTEP(s0, Kb0, 1) QKSTEP(s0, Kb0, 2) QKSTEP(s0, Kb0, 3)
        QKSTEP(s0, Kb0, 4) QKSTEP(s0, Kb0, 5) QKSTEP(s0, Kb0, 6) QKSTEP(s0, Kb0, 7)
        __builtin_amdgcn_s_setprio(0);
    }

    for (int it = 0; it < NIT; it += 2) {
        FBODY(it, s0, s1)
        FBODY(it + 1, s1, s0)
    }

    // ---- epilogue: row-sums + staged coalesced O-partial store ----
    {
        float lsum = lsum0 + lsum1;
        float tot = lsum + __shfl_xor(lsum, 32);
        if (lane < 32)
            lsums[((size_t)ks * BB + b) * NN + qb + wave * 32 + l31] = tot;
    }
    __syncthreads();  // full drain once: all waves done with ring bufs before Ox overlay
    unsigned short (*Ox)[136] = (unsigned short (*)[136])smem;  // 128 x 136 (34816 B)
#pragma unroll
    for (int df = 0; df < 4; df++)
#pragma unroll
        for (int r = 0; r < 16; r++) {
            int qr = (r & 3) + 8 * (r >> 2) + 4 * hi;
            Ox[wave * 32 + qr][df * 32 + l31] = f2bf(o[df][r]);
        }
    __syncthreads();
    unsigned short* op = opart + (((size_t)ks * BB + b) * NN + qb) * DD;
#pragma unroll
    for (int i = 0; i < 8; i++) {
        int idx = t + 256 * i;  // 0..2047
        int nr = idx >> 4, c0 = (idx & 15) * 8;
        *(short8*)(op + (size_t)nr * DD + c0) = *(const short8*)&Ox[nr][c0];
    }
}

// ---------------- kernel 4: combine partials + out = w_mask . y^T + b_mask + x ----------------
// grid (NN/64, 2, BB) = 1024 blocks (cs split) -> 4 blocks/CU (35 KB pool, Os overlays Ys).
// r5-verified version (was part of the faster 233.4 total).
__global__ __launch_bounds__(256) void k_maskout(
        const unsigned short* __restrict__ opart, const float* __restrict__ lsums,
        const float* __restrict__ w_mask, const float* __restrict__ b_mask,
        const float* __restrict__ x, float* __restrict__ out) {
    __shared__ __align__(16) unsigned char pool[35072];
    unsigned short (*Ys)[136] = (unsigned short (*)[136])pool;  // 64x136x2B = 17408
    float (*Os)[68] = (float (*)[68])pool;                       // 128x68x4B = 34816 (overlays Ys)
    float* invl = (float*)(pool + 34816);                        // 256 B
    int nb = blockIdx.x * 64, cs = blockIdx.y, b = blockIdx.z;
    int t = threadIdx.x, lane = t & 63, wave = t >> 6;
    int l16 = lane & 15, l4 = lane >> 4;

    const unsigned short* o0 = opart + ((size_t)b * NN + nb) * DD;
    const unsigned short* o1 = opart + (((size_t)BB + b) * NN + nb) * DD;
    if (t < 64) {
        float ls0 = lsums[(size_t)b * NN + nb + t];
        float ls1 = lsums[((size_t)BB + b) * NN + nb + t];
        invl[t] = 1.0f / (ls0 + ls1);
    }
    __syncthreads();
#pragma unroll
    for (int i = 0; i < 4; i++) {  // combine the 2 key-split partials while staging y
        int idx = t + 256 * i;
        int nr = idx >> 4, d0 = (idx & 15) * 8;
        short8 a = *(const short8*)(o0 + (size_t)nr * DD + d0);
        short8 c = *(const short8*)(o1 + (size_t)nr * DD + d0);
        float inv = invl[nr];
        short8 yv;
#pragma unroll
        for (int j = 0; j < 8; j++)
            yv[j] = (short)f2bf((bf2f((unsigned short)a[j]) + bf2f((unsigned short)c[j])) * inv);
        *(short8*)&Ys[nr][d0] = yv;
    }
    __syncthreads();

    f32x4 acc[2][4];
#pragma unroll
    for (int mf = 0; mf < 2; mf++)
#pragma unroll
        for (int nf = 0; nf < 4; nf++)
#pragma unroll
            for (int e = 0; e < 4; e++) acc[mf][nf][e] = 0.f;

#pragma unroll
    for (int kc = 0; kc < 4; kc++) {
        int d0 = kc * 32 + l4 * 8;
        short8 af[2];
#pragma unroll
        for (int mf = 0; mf < 2; mf++) {
            int c = cs * 128 + wave * 32 + mf * 16 + l16;
            const float* wp = w_mask + c * DD + d0;
            af[mf] = pack8(*(const float4*)wp, *(const float4*)(wp + 4));
        }
#pragma unroll
        for (int nf = 0; nf < 4; nf++) {
            short8 bfr = *(const short8*)&Ys[nf * 16 + l16][d0];
#pragma unroll
            for (int mf = 0; mf < 2; mf++)
                acc[mf][nf] = __builtin_amdgcn_mfma_f32_16x16x32_bf16(af[mf], bfr, acc[mf][nf], 0, 0, 0);
        }
    }
    __syncthreads();  // all Ys reads done; Os overlays Ys

    // stage acc + bias into Os[128][68] fp32 (writes 2-way bank-aliased)
#pragma unroll
    for (int mf = 0; mf < 2; mf++) {
        int c0 = wave * 32 + mf * 16 + l4 * 4;  // local c 0..127
        float bb[4];
#pragma unroll
        for (int r = 0; r < 4; r++) bb[r] = b_mask[cs * 128 + c0 + r];
#pragma unroll
        for (int r = 0; r < 4; r++)
#pragma unroll
            for (int nf = 0; nf < 4; nf++)
                Os[c0 + r][nf * 16 + l16] = acc[mf][nf][r] + bb[r];
    }
    __syncthreads();

    // vectorized epilogue: out = Os + x (float4; 256B contiguous per c-row)
    const float* xp = x + (size_t)b * CC * NN + (size_t)cs * 128 * NN + nb;
    float* op = out + (size_t)b * CC * NN + (size_t)cs * 128 * NN + nb;
#pragma unroll
    for (int i = 0; i < 8; i++) {
        int idx = t + 256 * i;        // 0..2047
        int c = idx >> 4, nq = (idx & 15) * 4;
        float4 osv = *(const float4*)&Os[c][nq];
        float4 xv = *(const float4*)(xp + (size_t)c * NN + nq);
        float4 ov;
        ov.x = osv.x + xv.x; ov.y = osv.y + xv.y;
        ov.z = osv.z + xv.z; ov.w = osv.w + xv.w;
        *(float4*)(op + (size_t)c * NN + nq) = ov;
    }
}

extern "C" void kernel_launch(void* const* d_in, const int* in_sizes, int n_in,
                              void* d_out, int out_size, void* d_ws, size_t ws_size,
                              hipStream_t stream) {
    const float* x       = (const float*)d_in[0];
    const float* w_phi   = (const float*)d_in[1];
    const float* b_phi   = (const float*)d_in[2];
    const float* w_theta = (const float*)d_in[3];
    const float* b_theta = (const float*)d_in[4];
    const float* w_g     = (const float*)d_in[5];
    const float* b_g     = (const float*)d_in[6];
    const float* w_mask  = (const float*)d_in[7];
    const float* b_mask  = (const float*)d_in[8];
    float* out = (float*)d_out;

    // ws (48 MiB): [0,16M): Opart (2*8*4096*128 bf16 = 16 MiB)
    //              [16,24M): Q | [24,32M): K | [32,40M): Vt | [40M+): lsums (256 KiB)
    char* ws = (char*)d_ws;
    unsigned short* opart = (unsigned short*)(ws);
    unsigned short* qw    = (unsigned short*)(ws + ((size_t)16 << 20));
    unsigned short* kw    = (unsigned short*)(ws + ((size_t)24 << 20));
    unsigned short* vtw   = (unsigned short*)(ws + ((size_t)32 << 20));
    float*          lsums = (float*)(ws + ((size_t)40 << 20));

    k_proj<<<dim3(NN / 32, BB), 256, 0, stream>>>(x, w_phi, b_phi, w_theta, b_theta,
                                                  w_g, b_g, qw, kw, vtw);
    k_flash<<<dim3(512, 1, 1), 256, 0, stream>>>(qw, kw, vtw, opart, lsums);
    k_maskout<<<dim3(NN / 64, 2, BB), 256, 0, stream>>>(opart, lsums, w_mask, b_mask, x, out);
}